// Round 13
// baseline (663.640 us; speedup 1.0000x reference)
//
#include <hip/hip_runtime.h>
#include <hip/hip_bf16.h>

typedef unsigned short u16;
typedef __attribute__((ext_vector_type(8))) short bf16x8;
typedef __attribute__((ext_vector_type(2))) short s16x2;
typedef __attribute__((ext_vector_type(4))) float f32x4;

#define N_NODES 50000
#define EDGES 500000
#define WPT 31250     // 16-edge groups per type
#define EPB 2048      // persistent edge blocks per type-launch
#define EPW (EPB * 4) // persistent edge waves per type-launch (8192)
#define NWAVES 3125   // node waves per type (50000/16)
#define NBLK 782      // ceil(NWAVES/4)

__device__ __forceinline__ u16 f2bf(float f) {
  return __builtin_bit_cast(u16, __float2bfloat16(f));
}
__device__ __forceinline__ float bf2f(u16 u) {
  return __builtin_bit_cast(float, ((unsigned)u) << 16);
}
__device__ __forceinline__ float bfe(bf16x8 v, int j) {
  return bf2f((u16)v[j]);
}

// packed bf16 atomic add (2 values at 4B-aligned address)
__device__ __forceinline__ void pk_atomic_bf16(u16* addr, float lo, float hi) {
#if __has_builtin(__builtin_amdgcn_global_atomic_fadd_v2bf16)
  s16x2 v;
  v[0] = (short)f2bf(lo);
  v[1] = (short)f2bf(hi);
  __builtin_amdgcn_global_atomic_fadd_v2bf16(
      (__attribute__((address_space(1))) s16x2*)addr, v);
#else
  unsigned* p = (unsigned*)addr;
  unsigned old = *p, assumed;
  do {
    assumed = old;
    float l2 = bf2f((u16)(assumed & 0xffff)) + lo;
    float h2 = bf2f((u16)(assumed >> 16)) + hi;
    unsigned nv = (unsigned)f2bf(l2) | ((unsigned)f2bf(h2) << 16);
    old = atomicCAS(p, assumed, nv);
  } while (old != assumed);
#endif
}

// ---------------------------------------------------------------------------
// Combined prep: weights -> bf16 tables (9 x 128x128), msgX zeroing, AND
// x fp32 -> bf16 cast (r10's known-good version).
// blocks [0,576): weights; [576,6826): zero msgX; [6826,13076): cast x.
// ---------------------------------------------------------------------------
__global__ __launch_bounds__(256) void prep_all(
    const float* __restrict__ Wp, const float* __restrict__ Wc,
    const float* __restrict__ W1,
    const float* __restrict__ Wrel_ab, const float* __restrict__ Wroot_ab,
    const float* __restrict__ Wrel_ba, const float* __restrict__ Wroot_ba,
    const float* __restrict__ xa, const float* __restrict__ xb,
    u16* __restrict__ out, u16* __restrict__ msg,
    u16* __restrict__ xa_bf, u16* __restrict__ xb_bf)
{
  if (blockIdx.x >= 6826) {
    // cast 2 * 50000 * 128 fp32 -> bf16, 8 elems/thread, 6250 blocks
    int t = (blockIdx.x - 6826) * 256 + threadIdx.x;
    const int HALF = (N_NODES * 128) / 8;   // 800000
    const float* src;
    u16* dst;
    int idx;
    if (t < HALF) { src = xa; dst = xa_bf; idx = t * 8; }
    else          { src = xb; dst = xb_bf; idx = (t - HALF) * 8; }
    f32x4 a = *(const f32x4*)(src + idx);
    f32x4 b = *(const f32x4*)(src + idx + 4);
    bf16x8 o;
#pragma unroll
    for (int j = 0; j < 4; j++) {
      o[j]     = (short)f2bf(a[j]);
      o[j + 4] = (short)f2bf(b[j]);
    }
    *(bf16x8*)(dst + idx) = o;
    return;
  }
  if (blockIdx.x >= 576) {
    // zero 2 * N_NODES * 128 bf16, 8 per thread, 6250 blocks
    size_t t = (size_t)(blockIdx.x - 576) * 256 + threadIdx.x;
    bf16x8 z = {0, 0, 0, 0, 0, 0, 0, 0};
    *(bf16x8*)(msg + t * 8) = z;
    return;
  }
  int tid = blockIdx.x * 256 + threadIdx.x;  // 9*16384
  int m = tid >> 14;
  int idx = tid & 16383;
  int r = idx >> 7;
  int c = idx & 127;
  float val;
  switch (m) {
    case 0: val = Wp[r * 128 + c]; break;
    case 1: val = Wc[r * 128 + c]; break;
    case 2: val = W1[r * 384 + c]; break;
    case 3: val = W1[r * 384 + 128 + c]; break;
    case 4: val = W1[r * 384 + 256 + c]; break;
    case 5: val = Wrel_ab[r * 128 + c]; break;
    case 6: val = Wroot_ab[r * 128 + c]; break;
    case 7: val = Wrel_ba[r * 128 + c]; break;
    default: val = Wroot_ba[r * 128 + c]; break;
  }
  out[tid] = f2bf(val);
}

// ---------------------------------------------------------------------------
// Encoder u/v, one (type, chain, row-tile) task per wave (12500 tasks):
//   chain 0: u_t = lrelu(x_t@Wp^T+bp) @ W1a^T + b1
//   chain 1: v_t = lrelu(x_t@Wc^T+bc) @ W1b^T
// Reads the bf16 x table (prep casts). Half the per-wave serial chain and
// twice the wave count of the old encoder2 -> better latency hiding.
// ---------------------------------------------------------------------------
__global__ __launch_bounds__(256) void enc_uv(
    const u16* __restrict__ xa_bf, const u16* __restrict__ xb_bf,
    const u16* __restrict__ Wp_b, const float* __restrict__ bp,
    const u16* __restrict__ Wc_b, const float* __restrict__ bc,
    const u16* __restrict__ W1a_b, const float* __restrict__ b1,
    const u16* __restrict__ W1b_b,
    u16* __restrict__ u_a, u16* __restrict__ v_a,
    u16* __restrict__ u_b, u16* __restrict__ v_b)
{
  __shared__ u16 tile[4][2176];   // 16 x pitch 136 bf16, per wave
  int widx = threadIdx.x >> 6;
  int w = blockIdx.x * 4 + widx;        // 0..12503
  if (w > 12499) w = 12499;             // clamp (dup of last task; same-value
                                        // stores, benign)
  int type = w / 6250;
  int rem = w - type * 6250;
  int chain = rem / 3125;
  int nw = rem - chain * 3125;

  const u16* xbf = type ? xb_bf : xa_bf;
  const u16* Wenc = chain ? Wc_b : Wp_b;
  const float* benc = chain ? bc : bp;
  const u16* Wmix = chain ? W1b_b : W1a_b;
  const float* bmix = chain ? (const float*)nullptr : b1;
  u16* outp = chain ? (type ? v_b : v_a) : (type ? u_b : u_a);

  int row0 = nw * 16;
  int lane = threadIdx.x & 63;
  int col = lane & 15;
  int quad = lane >> 4;
  u16* tl = tile[widx];

  bf16x8 af[4];
#pragma unroll
  for (int ks = 0; ks < 4; ks++)
    af[ks] = *(const bf16x8*)(xbf + (size_t)(row0 + col) * 128 + ks * 32 + quad * 8);

  f32x4 zero = {0.f, 0.f, 0.f, 0.f};
  f32x4 acc[8];
#pragma unroll
  for (int nt = 0; nt < 8; nt++) acc[nt] = zero;
#pragma unroll
  for (int ks = 0; ks < 4; ks++) {
    const u16* wp = Wenc + col * 128 + ks * 32 + quad * 8;
#pragma unroll
    for (int nt = 0; nt < 8; nt++) {
      bf16x8 bf = *(const bf16x8*)(wp + nt * 2048);
      acc[nt] = __builtin_amdgcn_mfma_f32_16x16x32_bf16(af[ks], bf, acc[nt], 0, 0, 0);
    }
  }
  // per-wave tile: in-wave lgkmcnt ordering suffices, no barrier
#pragma unroll
  for (int nt = 0; nt < 8; nt++) {
    float be = benc[nt * 16 + col];
#pragma unroll
    for (int r = 0; r < 4; r++) {
      float v = acc[nt][r] + be;
      v = v > 0.f ? v : 0.01f * v;
      tl[(quad * 4 + r) * 136 + nt * 16 + col] = f2bf(v);
    }
  }
  bf16x8 a2[4];
#pragma unroll
  for (int ks = 0; ks < 4; ks++)
    a2[ks] = *(const bf16x8*)&tl[col * 136 + ks * 32 + quad * 8];

  f32x4 acc2[8];
#pragma unroll
  for (int nt = 0; nt < 8; nt++) acc2[nt] = zero;
#pragma unroll
  for (int ks = 0; ks < 4; ks++) {
    const u16* wp = Wmix + col * 128 + ks * 32 + quad * 8;
#pragma unroll
    for (int nt = 0; nt < 8; nt++) {
      bf16x8 bf = *(const bf16x8*)(wp + nt * 2048);
      acc2[nt] = __builtin_amdgcn_mfma_f32_16x16x32_bf16(a2[ks], bf, acc2[nt], 0, 0, 0);
    }
  }
#pragma unroll
  for (int nt = 0; nt < 8; nt++) {
    float bm = bmix ? bmix[nt * 16 + col] : 0.f;
#pragma unroll
    for (int r = 0; r < 4; r++)
      outp[(size_t)(row0 + quad * 4 + r) * 128 + nt * 16 + col] = f2bf(acc2[nt][r] + bm);
  }
}

// ---------------------------------------------------------------------------
// Edge phase (r12 body, unchanged) PLUS piggybacked root-GEMM blocks:
// blockIdx >= EPB computes out = xs@Wroot^T + brel + broot for NWAVES row
// tiles — independent dense work that fills the ~89% idle wave slots during
// the latency-bound edge phase. xs is already in this launch's working set.
// ---------------------------------------------------------------------------
__global__ __launch_bounds__(256) void edge_root(
    const u16* __restrict__ xs, const u16* __restrict__ xd,
    const int* __restrict__ ei,
    const u16* __restrict__ W1c,
    const u16* __restrict__ uT, const u16* __restrict__ vT,
    const float* __restrict__ W2, const float* __restrict__ b2p,
    u16* __restrict__ msgX,
    const u16* __restrict__ Wroot, const float* __restrict__ brel,
    const float* __restrict__ broot, float* __restrict__ outp)
{
  __shared__ u16 tld[4][2176];   // 16 x pitch 136 bf16, per wave (17.4 KB)
  int widx = threadIdx.x >> 6;
  int lane = threadIdx.x & 63;
  int col = lane & 15;
  int quad = lane >> 4;

  f32x4 zero = {0.f, 0.f, 0.f, 0.f};

  if (blockIdx.x >= EPB) {
    // ---- root-GEMM path: out = xs@Wroot^T + brel + broot ----
    int nw = (blockIdx.x - EPB) * 4 + widx;
    if (nw >= NWAVES) return;
    int row0 = nw * 16;

    bf16x8 ax[4];
#pragma unroll
    for (int ks = 0; ks < 4; ks++)
      ax[ks] = *(const bf16x8*)(xs + (size_t)(row0 + col) * 128 + ks * 32 + quad * 8);

    f32x4 acc[8];
#pragma unroll
    for (int nt = 0; nt < 8; nt++) acc[nt] = zero;
#pragma unroll
    for (int ks = 0; ks < 4; ks++) {
      const u16* wp = Wroot + col * 128 + ks * 32 + quad * 8;
#pragma unroll
      for (int nt = 0; nt < 8; nt++) {
        bf16x8 bf = *(const bf16x8*)(wp + nt * 2048);
        acc[nt] = __builtin_amdgcn_mfma_f32_16x16x32_bf16(ax[ks], bf, acc[nt], 0, 0, 0);
      }
    }
#pragma unroll
    for (int nt = 0; nt < 8; nt++) {
      int c = nt * 16 + col;
      float b = brel[c] + broot[c];
#pragma unroll
      for (int r = 0; r < 4; r++)
        outp[(size_t)(row0 + quad * 4 + r) * 128 + c] = acc[nt][r] + b;
    }
    return;
  }

  // ---- edge path (identical to round-12's measured-optimal body) ----
  int wt = blockIdx.x * 4 + widx;   // 0..EPW-1
  int e4 = lane >> 2;
  int c0 = (lane & 3) * 32;
  u16* tl = tld[widx];
  float b2v = b2p[0];

  for (int g = wt; g < WPT; g += EPW) {
    int e0 = g * 16;

    int si = ei[e0 + col];
    int di = ei[EDGES + e0 + col];
    int s2 = ei[e0 + e4];
    int d2 = ei[EDGES + e0 + e4];

    // x gathers (col-layout) — feed the MFMA chain; af kept for the scatter
    bf16x8 af[4], d8[4];
#pragma unroll
    for (int ks = 0; ks < 4; ks++) {
      af[ks] = *(const bf16x8*)(xs + (size_t)si * 128 + ks * 32 + quad * 8);
      d8[ks] = *(const bf16x8*)(xd + (size_t)di * 128 + ks * 32 + quad * 8);
    }

    // df = |par - cld|  (d8 dies here)
    bf16x8 df[4];
#pragma unroll
    for (int ks = 0; ks < 4; ks++)
#pragma unroll
      for (int j = 0; j < 8; j++)
        df[ks][j] = (short)f2bf(__builtin_fabsf(bfe(af[ks], j) - bfe(d8[ks], j)));

    // 32 MFMAs (t = d @ W1c^T)
    f32x4 acc[8];
#pragma unroll
    for (int nt = 0; nt < 8; nt++) acc[nt] = zero;
#pragma unroll
    for (int ks = 0; ks < 4; ks++) {
      const u16* wp = W1c + col * 128 + ks * 32 + quad * 8;
#pragma unroll
      for (int nt = 0; nt < 8; nt++) {
        bf16x8 bf = *(const bf16x8*)(wp + nt * 2048);
        acc[nt] = __builtin_amdgcn_mfma_f32_16x16x32_bf16(df[ks], bf, acc[nt], 0, 0, 0);
      }
    }

    // u/v gathers (edge-major) — TLP covers the latency
    const u16* urow = uT + (size_t)s2 * 128 + c0;
    const u16* vrow = vT + (size_t)d2 * 128 + c0;
    bf16x8 UU[4], VV[4];
#pragma unroll
    for (int k = 0; k < 4; k++) {
      UU[k] = *(const bf16x8*)(urow + k * 8);
      VV[k] = *(const bf16x8*)(vrow + k * 8);
    }

    // t -> tile (C-layout -> edge-major); acc dies here
#pragma unroll
    for (int nt = 0; nt < 8; nt++)
#pragma unroll
      for (int r = 0; r < 4; r++)
        tl[(quad * 4 + r) * 136 + nt * 16 + col] = f2bf(acc[nt][r]);

    // edge-major epilogue: w = sigmoid(W2 . relu(t + u + v) + b2)
    const u16* trow = &tl[e4 * 136 + c0];
    float p = 0.f;
#pragma unroll
    for (int k = 0; k < 4; k++) {
      bf16x8 tt = *(const bf16x8*)(trow + k * 8);
      f32x4 w0 = *(const f32x4*)(W2 + c0 + k * 8);
      f32x4 w1 = *(const f32x4*)(W2 + c0 + k * 8 + 4);
#pragma unroll
      for (int j = 0; j < 4; j++) {
        float q0 = bfe(tt, j) + bfe(UU[k], j) + bfe(VV[k], j);
        if (q0 > 0.f) p += q0 * w0[j];
        float q1 = bfe(tt, j + 4) + bfe(UU[k], j + 4) + bfe(VV[k], j + 4);
        if (q1 > 0.f) p += q1 * w1[j];
      }
    }
    p += __shfl_xor(p, 1, 64);
    p += __shfl_xor(p, 2, 64);
    float wgt = 1.f / (1.f + __expf(-(p + b2v)));

    // af -> same per-wave tile (t reads above are in-wave ordered),
    // then coalesced pk scatter (64B runs per dst row)
#pragma unroll
    for (int ks = 0; ks < 4; ks++)
      *(bf16x8*)&tl[col * 136 + ks * 32 + quad * 8] = af[ks];
#pragma unroll
    for (int r = 0; r < 4; r++) {
      int src_lane = (quad * 4 + r) * 4;
      float wr = __shfl(wgt, src_lane, 64);
      int dr = __shfl(d2, src_lane, 64);
      u16* mrow = msgX + (size_t)dr * 128;
      const u16* xrow = &tl[(quad * 4 + r) * 136];
#pragma unroll
      for (int nt = 0; nt < 4; nt++) {
        int c = nt * 32 + col * 2;
        unsigned xv = *(const unsigned*)(xrow + c);
        pk_atomic_bf16(mrow + c, wr * bf2f((u16)(xv & 0xffff)),
                                 wr * bf2f((u16)(xv >> 16)));
      }
    }
  }
}

// ---------------------------------------------------------------------------
// Final: out += msgX@Wrel^T (root part + biases already in out from the
// piggybacked blocks). fp32 read-modify-write, exclusive writer.
// ---------------------------------------------------------------------------
__global__ __launch_bounds__(256) void out_msg(
    const u16* __restrict__ msgX_a, const u16* __restrict__ msgX_b,
    const u16* __restrict__ Wrelba_b, const u16* __restrict__ Wrelab_b,
    float* __restrict__ out_a, float* __restrict__ out_b)
{
  int w = blockIdx.x * 4 + (threadIdx.x >> 6);
  int type = (w >= NBLK * 4) ? 1 : 0;
  int nw = w - type * NBLK * 4;
  if (nw >= NWAVES) return;
  const u16* msg = type ? msgX_b : msgX_a;
  const u16* Wrel = type ? Wrelab_b : Wrelba_b;
  float* outp = type ? out_b : out_a;
  int row0 = nw * 16;
  int lane = threadIdx.x & 63;
  int col = lane & 15;
  int quad = lane >> 4;

  bf16x8 am[4];
#pragma unroll
  for (int ks = 0; ks < 4; ks++)
    am[ks] = *(const bf16x8*)(msg + (size_t)(row0 + col) * 128 + ks * 32 + quad * 8);

  f32x4 zero = {0.f, 0.f, 0.f, 0.f};
  f32x4 acc[8];
#pragma unroll
  for (int nt = 0; nt < 8; nt++) acc[nt] = zero;
#pragma unroll
  for (int ks = 0; ks < 4; ks++) {
    const u16* wp = Wrel + col * 128 + ks * 32 + quad * 8;
#pragma unroll
    for (int nt = 0; nt < 8; nt++) {
      bf16x8 bf = *(const bf16x8*)(wp + nt * 2048);
      acc[nt] = __builtin_amdgcn_mfma_f32_16x16x32_bf16(am[ks], bf, acc[nt], 0, 0, 0);
    }
  }
#pragma unroll
  for (int nt = 0; nt < 8; nt++) {
    int c = nt * 16 + col;
#pragma unroll
    for (int r = 0; r < 4; r++) {
      size_t idx = (size_t)(row0 + quad * 4 + r) * 128 + c;
      outp[idx] = outp[idx] + acc[nt][r];
    }
  }
}

// ---------------------------------------------------------------------------
extern "C" void kernel_launch(void* const* d_in, const int* in_sizes, int n_in,
                              void* d_out, int out_size, void* d_ws, size_t ws_size,
                              hipStream_t stream) {
  const float* x_a      = (const float*)d_in[0];
  const float* x_b      = (const float*)d_in[1];
  const float* Wp       = (const float*)d_in[2];
  const float* bp       = (const float*)d_in[3];
  const float* Wc       = (const float*)d_in[4];
  const float* bc       = (const float*)d_in[5];
  const float* W1       = (const float*)d_in[6];
  const float* b1       = (const float*)d_in[7];
  const float* W2       = (const float*)d_in[8];
  const float* b2       = (const float*)d_in[9];
  const float* Wrel_ab  = (const float*)d_in[10];
  const float* brel_ab  = (const float*)d_in[11];
  const float* Wroot_ab = (const float*)d_in[12];
  const float* broot_ab = (const float*)d_in[13];
  const float* Wrel_ba  = (const float*)d_in[14];
  const float* brel_ba  = (const float*)d_in[15];
  const float* Wroot_ba = (const float*)d_in[16];
  const float* broot_ba = (const float*)d_in[17];
  const int*   ei_ab    = (const int*)d_in[18];
  const int*   ei_ba    = (const int*)d_in[19];

  char* ws = (char*)d_ws;
  u16* Wb        = (u16*)ws;               // 9*16384*2 B
  u16* Wp_b      = Wb + 0 * 16384;
  u16* Wc_b      = Wb + 1 * 16384;
  u16* W1a_b     = Wb + 2 * 16384;
  u16* W1b_b     = Wb + 3 * 16384;
  u16* W1c_b     = Wb + 4 * 16384;
  u16* Wrelab_b  = Wb + 5 * 16384;
  u16* Wrootab_b = Wb + 6 * 16384;
  u16* Wrelba_b  = Wb + 7 * 16384;
  u16* Wrootba_b = Wb + 8 * 16384;

  // 12.8 MB bf16 node tables
  u16* xa_bf   = (u16*)(ws + 1048576);
  u16* xb_bf   = (u16*)(ws + 13848576);
  u16* u_a     = (u16*)(ws + 26648576);
  u16* v_a     = (u16*)(ws + 39448576);
  u16* u_b     = (u16*)(ws + 52248576);
  u16* v_b     = (u16*)(ws + 65048576);
  u16* msgX_a  = (u16*)(ws + 77848576);    // contiguous pair, 25.6 MB total
  u16* msgX_b  = (u16*)(ws + 90648576);

  float* out_a = (float*)d_out;
  float* out_b = out_a + (size_t)N_NODES * 128;

  // 1. weights -> bf16 + msgX zeroing + x cast (576 + 6250 + 6250 blocks)
  prep_all<<<13076, 256, 0, stream>>>(Wp, Wc, W1, Wrel_ab, Wroot_ab,
                                      Wrel_ba, Wroot_ba, x_a, x_b,
                                      Wb, msgX_a, xa_bf, xb_bf);

  // 2. encoder u/v (split by type x chain: 12500 wave-tasks)
  enc_uv<<<3126, 256, 0, stream>>>(xa_bf, xb_bf, Wp_b, bp, Wc_b, bc,
                                   W1a_b, b1, W1b_b,
                                   u_a, v_a, u_b, v_b);

  // 3a. edge A->B (msg into msgX_b) + piggybacked out_a root-GEMM
  edge_root<<<EPB + NBLK, 256, 0, stream>>>(xa_bf, xb_bf, ei_ab, W1c_b,
                                            u_a, v_b, W2, b2, msgX_b,
                                            Wrootba_b, brel_ba, broot_ba, out_a);

  // 3b. edge B->A (msg into msgX_a) + piggybacked out_b root-GEMM
  edge_root<<<EPB + NBLK, 256, 0, stream>>>(xb_bf, xa_bf, ei_ba, W1c_b,
                                            u_b, v_a, W2, b2, msgX_a,
                                            Wrootab_b, brel_ab, broot_ab, out_b);

  // 4. final: out += msgX@Wrel^T
  out_msg<<<2 * NBLK, 256, 0, stream>>>(msgX_a, msgX_b,
                                        Wrelba_b, Wrelab_b, out_a, out_b);
}